// Round 6
// baseline (212.289 us; speedup 1.0000x reference)
//
#include <hip/hip_runtime.h>
#include <hip/hip_bf16.h>

// B=2048, N=512, D=8192.
// Pipeline (NO d_ws, NO atomics; scratch carved from d_out, per-block ownership):
//   1. m_norms:     mm[n]=||m_n||^2 -> p-slot (dead after rescore)
//   2. gemm_coarse: bf16 MFMA dot partials, 128x128 tile, splitK=8 -> m+sd (32 MB).
//                   r14: BK=64, KSTEPS=16 (half the steps, double work/step).
//                   Evidence: r9..r13 fixed FETCH(-72%), conflicts(->0), VALU
//                   (-50%), coalescing(x8), barrier drain -- dur PINNED at 58us
//                   = 4350 cyc/step, while per-step work sums to <=1500 cyc.
//                   => fixed per-STEP serialization (latency + 16-wave lockstep
//                   barrier convoy). Halving step count should halve it.
//                   LDS 2x(16+16)KB = 64KB, still 2 blocks/CU. Row stride is now
//                   128B (the G4 32-way-conflict case) -> 8-elem-block XOR
//                   swizzle block^=(row&7) applied on BOTH ds_write and ds_read:
//                   frag b128 reads spread 2-way uniform (free), staging b64
//                   writes 4/bank uniform (min service). K accumulation order
//                   unchanged (ascending) -> bit-identical output. One regset
//                   (r12: 1-ahead == 2-ahead) keeps VGPR<=128 for 4 waves/SIMD.
//                   Coalesced staging + XCD-pinned kc=bid&7 + raw lgkm-barrier kept.
//   3. rescore:     coarse argmin + margin candidates; exact f32 dots only if >=2
//                   candidates, CANDIDATE-PER-WAVE parallel; winner picked by
//                   index-ordered scan (deterministic under replay).
//   4. ema_scatter: grid (N,8); block (n,s) owns 1024-float slice s; 4-wave
//                   ballot-scan list build (per-wave sublists + prefix merge);
//                   16x/4x batched y-gather, exact-order EMA.

#define Bb 2048
#define Nn 512
#define Dd 8192
#define MARGIN 12.0f
#define KC 8
#define KSTEPS 16   // (Dd/KC)/64
#define BK 64

typedef __attribute__((ext_vector_type(4))) float f32x4;
typedef __attribute__((ext_vector_type(8))) short s16x8;
typedef __attribute__((ext_vector_type(2))) unsigned u32x2;

__device__ inline unsigned pack2(float lo, float hi) {
    return __builtin_amdgcn_perm(__float_as_uint(hi), __float_as_uint(lo), 0x07060302u);
}

__device__ inline void st4bf(unsigned short* dst, const float4 v) {
    u32x2 x;
    x[0] = pack2(v.x, v.y);
    x[1] = pack2(v.z, v.w);
    *(u32x2*)dst = x;          // 8B-aligned ds_write_b64
}

__device__ inline void ema4(float4& mcv, float4& scv, const float4 yv) {
#define EMA_C(c) { mcv.c = mcv.c * 0.001f + yv.c * 0.999f; \
                   float d_ = mcv.c - yv.c;                 \
                   scv.c = d_ * d_ * 0.001f + scv.c * 0.999f; }
    EMA_C(x) EMA_C(y) EMA_C(z) EMA_C(w)
#undef EMA_C
}

// ---------------- 1: m row norms ----------------
__global__ __launch_bounds__(256) void m_norms(const float* __restrict__ M,
                                               float* __restrict__ mm) {
    int n = blockIdx.x, t = threadIdx.x;
    const float4* r = (const float4*)(M + (size_t)n * Dd);
    float s = 0.f;
#pragma unroll
    for (int u = 0; u < 8; u++) {
        float4 v = r[t + 256 * u];
        s += v.x * v.x + v.y * v.y + v.z * v.z + v.w * v.w;
    }
    __shared__ float red[256];
    red[t] = s;
    __syncthreads();
    for (int off = 128; off > 0; off >>= 1) {
        if (t < off) red[t] += red[t + off];
        __syncthreads();
    }
    if (t == 0) mm[n] = red[0];
}

// ---------------- 2: coarse bf16 MFMA GEMM (dot only), splitK=8 ----------------
// 1-D grid 512 blocks, 512 threads (8 waves). Decode: kc = bid&7 (XCD-pinned),
// ct = (bid>>3)&3, rt = bid>>5. Tile 128x128, K-chunk 1024 (16 steps of 64).
// Wave w: rows (w&3)*32..+31, cols (w>>2)*64..+63.
// Staging: thread t -> rows {t>>3, t>>3+64}; per row, float4 at cols (t&7)*4
// and 32+(t&7)*4 (both wave-coalesced: 8 lanes cover 128B contiguously).
// LDS layout: row*64 elems, 8-elem blocks XOR-swizzled by row&7.
__global__ __launch_bounds__(512, 4) void gemm_coarse(const float* __restrict__ Y,
                                                      const float* __restrict__ M,
                                                      float* __restrict__ part) {
    __shared__ __align__(16) unsigned short As[2][128 * BK];
    __shared__ __align__(16) unsigned short Bs[2][128 * BK];
    const int t = threadIdx.x;
    const int lane = t & 63;
    const int w = t >> 6;

    const int bid = blockIdx.x;
    const int kc = bid & 7;          // one kc chunk per XCD
    const int ct = (bid >> 3) & 3;
    const int rt = bid >> 5;

    const size_t ybase = (size_t)rt * 128 * Dd + (size_t)kc * (KSTEPS * BK);
    const size_t mbase = (size_t)ct * 128 * Dd + (size_t)kc * (KSTEPS * BK);

    // coalesced staging geometry: rows rL and rL+64, cols c8*4 and 32+c8*4
    const int rL = t >> 3;
    const int c8 = t & 7;
    const float* gA0 = Y + ybase + (size_t)rL * Dd + c8 * 4;
    const float* gB0 = M + mbase + (size_t)rL * Dd + c8 * 4;
    // LDS dest (swizzled): col_lin = h*32 + c8*4; block = col_lin>>3 ^ (row&7);
    // (rL+64)&7 == rL&7, so row rL+64 = same swizzle, offset +64*BK.
    const int swz = rL & 7;
    const int dA0 = rL * BK + ((((c8 >> 1) + 0) ^ swz) << 3) + (c8 & 1) * 4;  // half 0
    const int dA1 = rL * BK + ((((c8 >> 1) + 4) ^ swz) << 3) + (c8 & 1) * 4;  // half 1

    const int wr0 = (w & 3) * 32, wc0 = (w >> 2) * 64;
    const int l15 = lane & 15, quad = lane >> 4;

    f32x4 acc[2][4];
#pragma unroll
    for (int i = 0; i < 2; i++)
#pragma unroll
        for (int j = 0; j < 4; j++) acc[i][j] = (f32x4)(0.0f);

    // one staging register set (r12: 1-ahead == 2-ahead; keeps VGPR <= 128)
    float4 rA00, rA01, rA10, rA11;   // A: row{0,1} x half{0,1}
    float4 rB00, rB01, rB10, rB11;   // B: row{0,1} x half{0,1}
    const size_t rowskip = (size_t)64 * Dd;

    auto loads = [&](int step) {
        const float* pa = gA0 + step * BK;
        const float* pb = gB0 + step * BK;
        rA00 = *(const float4*)pa;             rA01 = *(const float4*)(pa + 32);
        rA10 = *(const float4*)(pa + rowskip); rA11 = *(const float4*)(pa + rowskip + 32);
        rB00 = *(const float4*)pb;             rB01 = *(const float4*)(pb + 32);
        rB10 = *(const float4*)(pb + rowskip); rB11 = *(const float4*)(pb + rowskip + 32);
    };
    auto writes = [&](int buf) {
        st4bf(&As[buf][dA0],            rA00);
        st4bf(&As[buf][dA1],            rA01);
        st4bf(&As[buf][dA0 + 64 * BK],  rA10);
        st4bf(&As[buf][dA1 + 64 * BK],  rA11);
        st4bf(&Bs[buf][dA0],            rB00);
        st4bf(&Bs[buf][dA1],            rB01);
        st4bf(&Bs[buf][dA0 + 64 * BK],  rB10);
        st4bf(&Bs[buf][dA1 + 64 * BK],  rB11);
    };
    auto compute = [&](int buf) {
#pragma unroll
        for (int ks = 0; ks < 2; ks++) {
            s16x8 fa[2], fb[4];
#pragma unroll
            for (int ta = 0; ta < 2; ta++) {
                int row = wr0 + ta * 16 + l15;
                int blk = (ks * 4 + quad) ^ (row & 7);
                fa[ta] = *(const s16x8*)(&As[buf][row * BK + (blk << 3)]);
            }
#pragma unroll
            for (int tb = 0; tb < 4; tb++) {
                int row = wc0 + tb * 16 + l15;
                int blk = (ks * 4 + quad) ^ (row & 7);
                fb[tb] = *(const s16x8*)(&Bs[buf][row * BK + (blk << 3)]);
            }
#pragma unroll
            for (int i = 0; i < 2; i++)
#pragma unroll
                for (int j = 0; j < 4; j++)
                    acc[i][j] = __builtin_amdgcn_mfma_f32_16x16x32_bf16(fa[i], fb[j], acc[i][j], 0, 0, 0);
        }
    };

    // RAW barrier: ds_writes made visible with lgkmcnt(0) ONLY (staging loads
    // target VGPRs; no vmem drain needed for cross-wave correctness).
#define BARRIER() do {                                          \
        asm volatile("s_waitcnt lgkmcnt(0)" ::: "memory");      \
        __builtin_amdgcn_s_barrier();                           \
    } while (0)

    loads(0);
    writes(0);
    BARRIER();
    for (int step = 0; step < KSTEPS; step++) {
        const int buf = step & 1;
        if (step + 1 < KSTEPS) loads(step + 1);
        compute(buf);
        if (step + 1 < KSTEPS) writes(buf ^ 1);
        BARRIER();
    }
#undef BARRIER

    // store partials; C/D layout: col = lane&15, row = quad*4 + reg
    float* P = part + (size_t)kc * (Bb * Nn);
#pragma unroll
    for (int i = 0; i < 2; i++) {
        int rg = rt * 128 + wr0 + i * 16 + quad * 4;
#pragma unroll
        for (int j = 0; j < 4; j++) {
            int cg = ct * 128 + wc0 + j * 16 + l15;
#pragma unroll
            for (int r = 0; r < 4; r++)
                P[(size_t)(rg + r) * Nn + cg] = acc[i][j][r];
        }
    }
}

// ---------------- 3: coarse argmin + wave-parallel exact rescore ----------------
__global__ __launch_bounds__(256) void rescore(const float* __restrict__ Y,
                                               const float* __restrict__ M,
                                               const float* __restrict__ part,
                                               const float* __restrict__ mm,
                                               float* __restrict__ assignF) {
    __shared__ float redW[4];
    __shared__ int candList[Nn];
    __shared__ float candD2[Nn];
    __shared__ int candCnt;
    int b = blockIdx.x, t = threadIdx.x, lane = t & 63, w = t >> 6;
    if (t == 0) candCnt = 0;

    int c0 = t, c1 = t + 256;
    float dot0 = 0.f, dot1 = 0.f;
#pragma unroll
    for (int k = 0; k < KC; k++) {
        dot0 += part[(size_t)k * (Bb * Nn) + (size_t)b * Nn + c0];
        dot1 += part[(size_t)k * (Bb * Nn) + (size_t)b * Nn + c1];
    }
    float d0 = mm[c0] - 2.0f * dot0;
    float d1 = mm[c1] - 2.0f * dot1;

    float mn = fminf(d0, d1);
#pragma unroll
    for (int off = 32; off > 0; off >>= 1) mn = fminf(mn, __shfl_xor(mn, off));
    if (lane == 0) redW[w] = mn;
    __syncthreads();
    float thresh = fminf(fminf(redW[0], redW[1]), fminf(redW[2], redW[3])) + MARGIN;

    if (d0 <= thresh) candList[atomicAdd(&candCnt, 1)] = c0;
    if (d1 <= thresh) candList[atomicAdd(&candCnt, 1)] = c1;
    __syncthreads();
    int ncand = candCnt;

    if (ncand == 1) {                 // uncontested coarse winner: exact dot unnecessary
        if (t == 0) assignF[b] = (float)candList[0];
        return;
    }

    // each wave handles candidates j = w, w+4, ... (full-row dot per wave)
    const float4* yr = (const float4*)(Y + (size_t)b * Dd);
    for (int j = w; j < ncand; j += 4) {
        int c = candList[j];
        const float4* mr = (const float4*)(M + (size_t)c * Dd);
        float p = 0.f;
#pragma unroll 8
        for (int u = 0; u < 32; u++) {
            float4 yv = yr[u * 64 + lane];
            float4 mv = mr[u * 64 + lane];
            p += yv.x * mv.x + yv.y * mv.y + yv.z * mv.z + yv.w * mv.w;
        }
#pragma unroll
        for (int off = 32; off > 0; off >>= 1) p += __shfl_xor(p, off);
        if (lane == 0) candD2[j] = mm[c] - 2.0f * p;
    }
    __syncthreads();

    if (t == 0) {       // index-ordered scan: deterministic regardless of list order
        float bestV = 3.4e38f;
        int bestI = 0x3fffffff;
        for (int j = 0; j < ncand; j++) {
            float d2e = candD2[j];
            int c = candList[j];
            if (d2e < bestV || (d2e == bestV && c < bestI)) { bestV = d2e; bestI = c; }
        }
        assignF[b] = (float)bestI;
    }
}

// ---------------- 4: per-cluster sequential EMA, D-sliced x8, 4-wave list build --
__global__ __launch_bounds__(256) void ema_scatter(const float* __restrict__ Y,
                                                   const float* __restrict__ M0,
                                                   const float* __restrict__ SD0,
                                                   const float* __restrict__ P0,
                                                   const float* __restrict__ assignF,
                                                   float* __restrict__ m_out,
                                                   float* __restrict__ sd_out,
                                                   float* __restrict__ p_out) {
    __shared__ int lst[Bb];
    __shared__ int cnt4[4];
    int n = blockIdx.x, s = blockIdx.y, t = threadIdx.x, lane = t & 63, w = t >> 6;

    // all 4 waves scan: wave w owns u-range [w*8, w*8+8) -> ordered sublist;
    // merge via prefix of per-wave counts (list identical to serial scan).
    int eqf[8], myidx[8];
    int cntW = 0;
#pragma unroll
    for (int k = 0; k < 8; k++) {
        int u = w * 8 + k;
        int zi = (int)assignF[u * 64 + lane];
        int eq = (zi == n) ? 1 : 0;
        unsigned long long mask = __ballot(eq != 0);
        eqf[k] = eq;
        myidx[k] = cntW + (int)__popcll(mask & ((1ull << lane) - 1ull));
        cntW += (int)__popcll(mask);
    }
    if (lane == 0) cnt4[w] = cntW;
    __syncthreads();
    int off0 = 0;
#pragma unroll
    for (int q = 0; q < 4; q++) off0 += (q < w) ? cnt4[q] : 0;
    int cnt = cnt4[0] + cnt4[1] + cnt4[2] + cnt4[3];
#pragma unroll
    for (int k = 0; k < 8; k++)
        if (eqf[k]) lst[off0 + myidx[k]] = (w * 8 + k) * 64 + lane;
    if (t == 0 && s == 0) p_out[n] = P0[n] + (float)cnt;
    __syncthreads();

    size_t off = (size_t)n * Dd + (size_t)s * 1024;
    float4 mc = *(const float4*)(M0 + off + 4 * t);
    float4 sc = *(const float4*)(SD0 + off + 4 * t);

    int j = 0;
    for (; j + 16 <= cnt; j += 16) {     // 16x batched gathers, exact-order EMA
        float4 yv[16];
#pragma unroll
        for (int q = 0; q < 16; q++)
            yv[q] = *(const float4*)(Y + (size_t)lst[j + q] * Dd + (size_t)s * 1024 + 4 * t);
#pragma unroll
        for (int q = 0; q < 16; q++) ema4(mc, sc, yv[q]);
    }
    for (; j + 4 <= cnt; j += 4) {       // 4x batch tier (avg cluster size ~4)
        float4 yv[4];
#pragma unroll
        for (int q = 0; q < 4; q++)
            yv[q] = *(const float4*)(Y + (size_t)lst[j + q] * Dd + (size_t)s * 1024 + 4 * t);
#pragma unroll
        for (int q = 0; q < 4; q++) ema4(mc, sc, yv[q]);
    }
    for (; j < cnt; j++) {
        float4 yv = *(const float4*)(Y + (size_t)lst[j] * Dd + (size_t)s * 1024 + 4 * t);
        ema4(mc, sc, yv);
    }

    *(float4*)(m_out + off + 4 * t) = mc;
    *(float4*)(sd_out + off + 4 * t) = sc;
}

extern "C" void kernel_launch(void* const* d_in, const int* in_sizes, int n_in,
                              void* d_out, int out_size, void* d_ws, size_t ws_size,
                              hipStream_t stream) {
    const float* y  = (const float*)d_in[0];
    const float* m  = (const float*)d_in[1];
    const float* sd = (const float*)d_in[2];
    const float* p  = (const float*)d_in[3];

    float* out     = (float*)d_out;
    float* m_out   = out;                       // partials k=0..3 live here pre-rescore
    float* sd_out  = out + 4194304;             // partials k=4..7 live here pre-rescore
    float* p_out   = out + 8388608;             // also: mm norms (dead after rescore)
    float* assignF = out + 8389120;
    float* part    = out;                       // 8 x 1M floats = m+sd regions exactly

    m_norms    <<<Nn, 256, 0, stream>>>(m, p_out);
    gemm_coarse<<<dim3(512), 512, 0, stream>>>(y, m, part);
    rescore    <<<Bb, 256, 0, stream>>>(y, m, part, p_out, assignF);
    ema_scatter<<<dim3(Nn, 8), 256, 0, stream>>>(y, m, sd, p, assignF, m_out, sd_out, p_out);
}